// Round 7
// baseline (1124.222 us; speedup 1.0000x reference)
//
#include <hip/hip_runtime.h>

typedef __attribute__((ext_vector_type(8))) short bf16x8;
typedef __attribute__((ext_vector_type(4))) float f32x4;
typedef __attribute__((ext_vector_type(4))) int i32x4;
typedef __attribute__((ext_vector_type(2))) int i32x2;

#define B_ 4
#define N_ 65536
#define RRR_ 32768
#define PADV_ 39304   // 34^3
#define PPLANE_ 1156  // 34*34

// ---- workspace layout (float offsets) ----
static const size_t OFF_NC     = 0;         //  [4][3][65536] f32
static const size_t OFF_VIDX   = 786432;    //  [4][65536] int
static const size_t OFF_WT1    = 1048576;   //  [27][128][64] bf16 (quarter-swizzled rows)
static const size_t OFF_WT2    = 1159168;   //  [54][128][64] bf16 (quarter-swizzled rows)
static const size_t OFF_C2OUT  = 1380352;   //  [4][32768][128] bf16
// ---- memset region starts here ----
static const size_t OFF_CNT    = 9768960;   //  [4][32768] f32
static const size_t OFF_GSUM   = 9900032;   //  [4][32768][64] f32
static const size_t OFF_GPAD   = 18288640;  //  [4][39304][64] bf16
static const size_t OFF_ACT1   = 23319552;  //  [4][39304][128] bf16
static const size_t OFF_GSTATS = 33381376;  //  [3][4][8][2] f32 raw sum/ssq
static const size_t OFF_BSTATS = 33381568;  //  [4][4] f32 (sum x3, maxbits)
static const size_t MEMSET_FLOATS = 33381584 - 9768960;

__device__ __forceinline__ ushort f2bf(float x) {
    union { float f; unsigned u; } c; c.f = x;
    unsigned r = c.u + 0x7fffu + ((c.u >> 16) & 1u);
    return (ushort)(r >> 16);
}
__device__ __forceinline__ float bf2f(ushort h) {
    union { unsigned u; float f; } c; c.u = ((unsigned)h) << 16;
    return c.f;
}

__device__ __forceinline__ void gl16(const void* g, void* l) {
    __builtin_amdgcn_global_load_lds(
        (const __attribute__((address_space(1))) unsigned int*)(g),
        (__attribute__((address_space(3))) unsigned int*)(l),
        16, 0, 0);
}

// ---------------- coord partial sums ----------------
__global__ __launch_bounds__(256) void k_coord_sum(const float* __restrict__ coords,
                                                   float* __restrict__ bstats) {
    int b = blockIdx.y;
    int tid = threadIdx.x;
    const float* cb = coords + (size_t)b * 3 * N_;
    float s0 = 0.f, s1 = 0.f, s2 = 0.f;
    for (int n = blockIdx.x * 256 + tid; n < N_; n += 64 * 256) {
        s0 += cb[n]; s1 += cb[N_ + n]; s2 += cb[2 * N_ + n];
    }
    #pragma unroll
    for (int off = 1; off < 64; off <<= 1) {
        s0 += __shfl_xor(s0, off);
        s1 += __shfl_xor(s1, off);
        s2 += __shfl_xor(s2, off);
    }
    if ((tid & 63) == 0) {
        atomicAdd(&bstats[b * 4 + 0], s0);
        atomicAdd(&bstats[b * 4 + 1], s1);
        atomicAdd(&bstats[b * 4 + 2], s2);
    }
}

// ---------------- coord max-norm (after sums) ----------------
__global__ __launch_bounds__(256) void k_coord_max(const float* __restrict__ coords,
                                                   float* __restrict__ bstats) {
    int b = blockIdx.y;
    int tid = threadIdx.x;
    const float invN = 1.0f / (float)N_;
    float m0 = bstats[b * 4 + 0] * invN;
    float m1 = bstats[b * 4 + 1] * invN;
    float m2 = bstats[b * 4 + 2] * invN;
    const float* cb = coords + (size_t)b * 3 * N_;
    float mx = 0.f;
    for (int n = blockIdx.x * 256 + tid; n < N_; n += 64 * 256) {
        float x = cb[n] - m0, y = cb[N_ + n] - m1, z = cb[2 * N_ + n] - m2;
        mx = fmaxf(mx, x * x + y * y + z * z);
    }
    #pragma unroll
    for (int off = 1; off < 64; off <<= 1)
        mx = fmaxf(mx, __shfl_xor(mx, off));
    if ((tid & 63) == 0)
        atomicMax((int*)&bstats[b * 4 + 3], __float_as_int(mx));
}

// ---------------- normalized coords, voxel idx, counts ----------------
__global__ __launch_bounds__(256) void k_point_prep(const float* __restrict__ coords,
                                                    const float* __restrict__ bstats,
                                                    float* __restrict__ nc,
                                                    int* __restrict__ vidx,
                                                    float* __restrict__ cnt) {
    int gid = blockIdx.x * 256 + threadIdx.x;
    int b = gid >> 16;
    int n = gid & (N_ - 1);
    const float invN = 1.0f / (float)N_;
    float m[3] = {bstats[b * 4 + 0] * invN, bstats[b * 4 + 1] * invN, bstats[b * 4 + 2] * invN};
    float den = 2.0f * sqrtf(__int_as_float(((const int*)bstats)[b * 4 + 3]));
    const float* cb = coords + (size_t)b * 3 * N_;
    int vi[3];
    #pragma unroll
    for (int d = 0; d < 3; ++d) {
        float cv = cb[(size_t)d * N_ + n];
        float t = (cv - m[d]) / den + 0.5f;
        t *= 32.0f;
        t = fminf(fmaxf(t, 0.0f), 31.0f);
        nc[((size_t)b * 3 + d) * N_ + n] = t;
        vi[d] = (int)rintf(t);
    }
    int flat = (vi[0] * 32 + vi[1]) * 32 + vi[2];
    vidx[(b << 16) + n] = flat;
    atomicAdd(&cnt[(b << 15) + flat], 1.0f);
}

// ---------------- scatter-add features (channels-last, LDS staged) ----------------
__global__ __launch_bounds__(256) void k_scatter_cl(const float* __restrict__ feats,
                                                    const int* __restrict__ vidx,
                                                    float* __restrict__ gsum) {
    __shared__ float lf[64 * 129];
    __shared__ int sidx[128];
    int tid = threadIdx.x;
    int b = blockIdx.y;
    int n0 = blockIdx.x * 128;
    for (int i = tid; i < 64 * 128; i += 256) {
        int ci = i >> 7, pt = i & 127;
        lf[ci * 129 + pt] = feats[((size_t)(b * 64 + ci)) * N_ + n0 + pt];
    }
    if (tid < 128) sidx[tid] = vidx[(b << 16) + n0 + tid];
    __syncthreads();
    for (int i = tid; i < 64 * 128; i += 256) {
        int ci = i & 63, pt = i >> 6;
        atomicAdd(&gsum[((size_t)(b << 15) + sidx[pt]) * 64 + ci], lf[ci * 129 + pt]);
    }
}

// ---------------- sum -> mean, to padded bf16 channels-last ----------------
__global__ __launch_bounds__(256) void k_gridmean_cl(const float* __restrict__ gsum,
                                                     const float* __restrict__ cnt,
                                                     ushort* __restrict__ gpad) {
    int idx = blockIdx.x * 256 + threadIdx.x;     // 4*32768*16
    int q = idx & 15;
    int vox = (idx >> 4) & 32767;
    int b = idx >> 19;
    float c = cnt[(b << 15) + vox];
    float inv = 1.0f / fmaxf(c, 1.0f);
    float4 v = *(const float4*)(gsum + (((size_t)(b << 15) + vox) << 6) + q * 4);
    int zz = vox >> 10, yy = (vox >> 5) & 31, xx = vox & 31;
    size_t o = ((size_t)b * PADV_ + (size_t)(zz + 1) * PPLANE_ + (yy + 1) * 34 + (xx + 1)) * 64 + q * 4;
    i32x2 pk;
    ushort* u = (ushort*)&pk;
    u[0] = f2bf(v.x * inv); u[1] = f2bf(v.y * inv);
    u[2] = f2bf(v.z * inv); u[3] = f2bf(v.w * inv);
    *(i32x2*)(gpad + o) = pk;
}

// ---------------- weight transform to [ks][co][64ch window], quarter-swizzled ----------------
// stored quarter jm of row co holds logical quarter (jm ^ (co&7)) of the K-window
template <int CI>
__global__ __launch_bounds__(256) void k_wtrans(const float* __restrict__ w,
                                                ushort* __restrict__ wt) {
    int idx = blockIdx.x * 256 + threadIdx.x;
    if (idx >= 27 * 128 * CI) return;
    int e = idx & 7;
    int jm = (idx >> 3) & 7;
    int co = (idx >> 6) & 127;
    int ks = idx >> 13;
    int q = jm ^ (co & 7);
    int tap = (CI == 64) ? ks : (ks >> 1);
    int ci = ((CI == 64) ? 0 : ((ks & 1) * 64)) + q * 8 + e;
    wt[idx] = f2bf(w[((size_t)co * CI + ci) * 27 + tap]);
}

// ---------------- 3^3 conv as implicit GEMM, global_load_lds 2-phase dbuf ----------------
// block: 128 pos (4y x 32x, z fixed) x 128 co, 256 thr / 4 waves (2 pos x 2 co)
// K-step 64. LDS: A[2][128 rows][128B] + B[2][128 co][128B] = 64 KB -> 2 blocks/CU
// Source-side quarter swizzle (q ^ (row&7)); LDS linear; swizzled ds_read.
template <int CI, bool PAD_OUT>
__global__ __launch_bounds__(256, 2) void k_conv(const ushort* __restrict__ inp,
                                                 const ushort* __restrict__ wt,
                                                 const float* __restrict__ bias,
                                                 ushort* __restrict__ outp,
                                                 float* __restrict__ gstats,
                                                 int layer) {
    constexpr int NK = 27 * CI / 64;
    __shared__ char lds[65536];

    const int yg = blockIdx.x, z0 = blockIdx.y, b = blockIdx.z;
    const int y0 = yg * 4;
    const int tid = threadIdx.x;
    const int w = tid >> 6, l = tid & 63;
    const int lk = l >> 4, lr = l & 15;
    const int wr = w >> 1, wc = w & 1;

    const char* actb = (const char*)(inp + (size_t)b * PADV_ * CI);
    const char* wtb = (const char*)wt;

    // per-inst A global base (tap 0, window 0), source-side swizzle folded
    const char* agp[4];
    #pragma unroll
    for (int i = 0; i < 4; ++i) {
        int s = tid + i * 256;
        int row = s >> 3, j = s & 7;
        int jj = j ^ (row & 7);
        int py = row >> 5, px = row & 31;
        agp[i] = actb + ((size_t)(z0 * PPLANE_ + (y0 + py) * 34 + px) * CI) * 2 + jj * 16;
    }
    char* ldsAw = lds + w * 1024;            // + cur*16384 + i*4096
    char* ldsBw = lds + 32768 + w * 1024;    // + cur*16384 + i*4096

    // fragment read offsets (swizzled)
    int ard[4][2], brd[4][2];
    #pragma unroll
    for (int i = 0; i < 4; ++i) {
        int pos = wr * 64 + i * 16 + lr;
        #pragma unroll
        for (int kk = 0; kk < 2; ++kk)
            ard[i][kk] = pos * 128 + (((kk * 4 + lk) ^ (pos & 7)) << 4);
    }
    #pragma unroll
    for (int n = 0; n < 4; ++n) {
        int co = wc * 64 + n * 16 + lr;
        #pragma unroll
        for (int kk = 0; kk < 2; ++kk)
            brd[n][kk] = co * 128 + (((kk * 4 + lk) ^ (co & 7)) << 4);
    }

    f32x4 acc[4][4];
    #pragma unroll
    for (int i = 0; i < 4; ++i)
        #pragma unroll
        for (int n = 0; n < 4; ++n)
            acc[i][n] = (f32x4){0.f, 0.f, 0.f, 0.f};

    auto stage = [&](int ks, int cur) {
        int tap = (CI == 64) ? ks : (ks >> 1);
        int choff2 = (CI == 64) ? 0 : ((ks & 1) << 7);
        int fz = tap / 9, r9 = tap - fz * 9;
        int fy = r9 / 3, fx = r9 - fy * 3;
        int ad = (fz * PPLANE_ + fy * 34 + fx) * CI * 2 + choff2;
        #pragma unroll
        for (int i = 0; i < 4; ++i)
            gl16(agp[i] + ad, ldsAw + cur * 16384 + i * 4096);
        const char* wsrc = wtb + (size_t)ks * 16384 + tid * 16;
        #pragma unroll
        for (int i = 0; i < 4; ++i)
            gl16(wsrc + i * 4096, ldsBw + cur * 16384 + i * 4096);
    };

    stage(0, 0);
    asm volatile("s_waitcnt vmcnt(0)" ::: "memory");
    __syncthreads();

    #pragma unroll 2
    for (int ks = 0; ks < NK; ++ks) {
        const int cur = ks & 1;
        if (ks + 1 < NK) stage(ks + 1, cur ^ 1);
        const char* Ac = lds + cur * 16384;
        const char* Bc = lds + 32768 + cur * 16384;
        #pragma unroll
        for (int kk = 0; kk < 2; ++kk) {
            bf16x8 af[4], bfr[4];
            #pragma unroll
            for (int i = 0; i < 4; ++i) af[i] = *(const bf16x8*)(Ac + ard[i][kk]);
            #pragma unroll
            for (int n = 0; n < 4; ++n) bfr[n] = *(const bf16x8*)(Bc + brd[n][kk]);
            #pragma unroll
            for (int i = 0; i < 4; ++i)
                #pragma unroll
                for (int n = 0; n < 4; ++n)
                    acc[i][n] = __builtin_amdgcn_mfma_f32_16x16x32_bf16(af[i], bfr[n], acc[i][n], 0, 0, 0);
        }
        asm volatile("s_waitcnt vmcnt(0)" ::: "memory");
        __syncthreads();
    }

    // ---- epilogue: bias + fused GN stats + bf16 pack via LDS + coalesced dump ----
    ushort* outs = (ushort*)lds;
    float bb[4];
    #pragma unroll
    for (int n = 0; n < 4; ++n) bb[n] = bias[wc * 64 + n * 16 + lr];
    float sg[4] = {0.f, 0.f, 0.f, 0.f}, sq[4] = {0.f, 0.f, 0.f, 0.f};
    #pragma unroll
    for (int i = 0; i < 4; ++i) {
        int posb = wr * 64 + i * 16 + lk * 4;
        #pragma unroll
        for (int n = 0; n < 4; ++n) {
            int co = wc * 64 + n * 16 + lr;
            #pragma unroll
            for (int r = 0; r < 4; ++r) {
                float v = acc[i][n][r] + bb[n];
                sg[n] += v; sq[n] += v * v;
                outs[(posb + r) * 128 + co] = f2bf(v);
            }
        }
    }
    #pragma unroll
    for (int off = 1; off < 64; off <<= 1) {
        #pragma unroll
        for (int n = 0; n < 4; ++n) {
            sg[n] += __shfl_xor(sg[n], off);
            sq[n] += __shfl_xor(sq[n], off);
        }
    }
    if (l == 0) {
        int gbase = layer * 32 + b * 8 + wc * 4;
        #pragma unroll
        for (int n = 0; n < 4; ++n) {
            atomicAdd(&gstats[(gbase + n) * 2 + 0], sg[n]);
            atomicAdd(&gstats[(gbase + n) * 2 + 1], sq[n]);
        }
    }
    __syncthreads();
    for (int idx = tid; idx < 2048; idx += 256) {
        int pos = idx >> 4, c8 = idx & 15;
        int yy = y0 + (pos >> 5), xx = pos & 31;
        size_t g;
        if (PAD_OUT)
            g = ((size_t)b * PADV_ + (size_t)(z0 + 1) * PPLANE_ + (yy + 1) * 34 + (xx + 1)) * 128 + c8 * 8;
        else
            g = ((size_t)b * RRR_ + z0 * 1024 + yy * 32 + xx) * 128 + c8 * 8;
        *(i32x4*)(outp + g) = *((i32x4*)lds + idx);
    }
}

// ---------------- GN + SiLU apply (channels-last bf16, padded or flat) ----------------
template <bool PAD>
__global__ __launch_bounds__(256) void k_gn_apply(ushort* __restrict__ x,
                                                  const float* __restrict__ gstats,
                                                  const float* __restrict__ sc,
                                                  const float* __restrict__ bi,
                                                  int layer, float invc) {
    int idx = blockIdx.x * 256 + threadIdx.x;   // 4*32768*16
    int c8 = idx & 15;
    int vox = (idx >> 4) & 32767;
    int b = idx >> 19;
    size_t base;
    if (PAD) {
        int zz = vox >> 10, yy = (vox >> 5) & 31, xx = vox & 31;
        base = ((size_t)b * PADV_ + (size_t)(zz + 1) * PPLANE_ + (yy + 1) * 34 + (xx + 1)) * 128 + c8 * 8;
    } else {
        base = ((size_t)b * RRR_ + vox) * 128 + c8 * 8;
    }
    int g = c8 >> 1;
    float sum = gstats[(layer * 32 + b * 8 + g) * 2 + 0];
    float ssq = gstats[(layer * 32 + b * 8 + g) * 2 + 1];
    float mean = sum * invc;
    float var = ssq * invc - mean * mean;
    float rstd = rsqrtf(var + 1e-5f);
    i32x4 raw = *(i32x4*)(x + base);
    ushort* u = (ushort*)&raw;
    #pragma unroll
    for (int j = 0; j < 8; ++j) {
        int co = c8 * 8 + j;
        float v = bf2f(u[j]);
        v = (v - mean) * rstd * sc[co] + bi[co];
        v = v / (1.f + __expf(-v));
        u[j] = f2bf(v);
    }
    *(i32x4*)(x + base) = raw;
}

// ---------------- point MLP (1x1 conv) + fused GN stats ----------------
__global__ __launch_bounds__(256) void k_point_mlp(const float* __restrict__ feats,
                                                   const float* __restrict__ w,
                                                   const float* __restrict__ pb,
                                                   float* __restrict__ out,
                                                   float* __restrict__ gstats) {
    __shared__ float wl[64 * 132];
    __shared__ float sred[4][16];
    int tid = threadIdx.x;
    for (int i = tid; i < 128 * 64; i += 256) {
        int o = i >> 6, c = i & 63;
        wl[c * 132 + o] = w[i];
    }
    __syncthreads();
    int gid = blockIdx.x * 256 + tid;
    int b = gid >> 16, n = gid & (N_ - 1);
    const float* fb = feats + (size_t)b * 64 * N_ + n;
    float acc[128];
    #pragma unroll
    for (int o = 0; o < 128; ++o) acc[o] = 0.f;
    for (int c = 0; c < 64; ++c) {
        float f = fb[(size_t)c * N_];
        const float4* wr4 = (const float4*)&wl[c * 132];
        #pragma unroll
        for (int o4 = 0; o4 < 32; ++o4) {
            float4 wv = wr4[o4];
            acc[4 * o4 + 0] = fmaf(f, wv.x, acc[4 * o4 + 0]);
            acc[4 * o4 + 1] = fmaf(f, wv.y, acc[4 * o4 + 1]);
            acc[4 * o4 + 2] = fmaf(f, wv.z, acc[4 * o4 + 2]);
            acc[4 * o4 + 3] = fmaf(f, wv.w, acc[4 * o4 + 3]);
        }
    }
    float* ob = out + (size_t)b * 128 * N_ + n;
    float sg[8] = {0.f}, sq[8] = {0.f};
    #pragma unroll
    for (int o = 0; o < 128; ++o) {
        float v = acc[o] + pb[o];
        ob[(size_t)o * N_] = v;
        sg[o >> 4] += v;
        sq[o >> 4] += v * v;
    }
    #pragma unroll
    for (int off = 1; off < 64; off <<= 1) {
        #pragma unroll
        for (int g = 0; g < 8; ++g) {
            sg[g] += __shfl_xor(sg[g], off);
            sq[g] += __shfl_xor(sq[g], off);
        }
    }
    int wv = tid >> 6, l = tid & 63;
    if (l == 0) {
        #pragma unroll
        for (int g = 0; g < 8; ++g) { sred[wv][g] = sg[g]; sred[wv][8 + g] = sq[g]; }
    }
    __syncthreads();
    if (tid < 16) {
        float v = sred[0][tid] + sred[1][tid] + sred[2][tid] + sred[3][tid];
        int g = tid & 7, part = tid >> 3;
        atomicAdd(&gstats[(64 + b * 8 + g) * 2 + part], v);
    }
}

// ---------------- devoxelize + point GN/SiLU + add ----------------
__global__ __launch_bounds__(256) void k_devox_final(const float* __restrict__ nc,
                                                     const ushort* __restrict__ ht,
                                                     const float* __restrict__ gstats,
                                                     const float* __restrict__ scale,
                                                     const float* __restrict__ bias,
                                                     float* __restrict__ out) {
    __shared__ float vp[64][129];
    __shared__ int sidx[64][8];
    __shared__ float swt[64][8];
    int tid = threadIdx.x;
    int blk = blockIdx.x;               // B * N/64 = 4096
    int b = blk >> 10;
    int n0 = (blk & 1023) * 64;
    if (tid < 64) {
        int n = n0 + tid;
        float f0 = nc[(size_t)b * 3 * N_ + n];
        float f1 = nc[((size_t)b * 3 + 1) * N_ + n];
        float f2 = nc[((size_t)b * 3 + 2) * N_ + n];
        float l0 = floorf(f0), l1 = floorf(f1), l2 = floorf(f2);
        float r0 = f0 - l0, r1 = f1 - l1, r2 = f2 - l2;
        int i0 = (int)l0, i1 = (int)l1, i2 = (int)l2;
        int h0 = min(i0 + 1, 31), h1 = min(i1 + 1, 31), h2 = min(i2 + 1, 31);
        #pragma unroll
        for (int k = 0; k < 8; ++k) {
            int dx = (k >> 2) & 1, dy = (k >> 1) & 1, dz = k & 1;
            int ix = dx ? h0 : i0, iy = dy ? h1 : i1, iz = dz ? h2 : i2;
            float w = (dx ? r0 : 1.f - r0) * (dy ? r1 : 1.f - r1) * (dz ? r2 : 1.f - r2);
            sidx[tid][k] = (ix * 32 + iy) * 32 + iz;
            swt[tid][k] = w;
        }
    }
    __syncthreads();
    const ushort* hb = ht + (size_t)b * RRR_ * 128;
    for (int t = tid; t < 64 * 16; t += 256) {
        int c8 = t & 15, pt = t >> 4;
        float a[8] = {0.f, 0.f, 0.f, 0.f, 0.f, 0.f, 0.f, 0.f};
        #pragma unroll
        for (int k = 0; k < 8; ++k) {
            i32x4 raw = *(const i32x4*)(hb + (size_t)sidx[pt][k] * 128 + c8 * 8);
            ushort* u = (ushort*)&raw;
            float wk = swt[pt][k];
            #pragma unroll
            for (int j = 0; j < 8; ++j)
                a[j] = fmaf(wk, bf2f(u[j]), a[j]);
        }
        #pragma unroll
        for (int j = 0; j < 8; ++j)
            vp[pt][c8 * 8 + j] = a[j];
    }
    __syncthreads();
    const float invc = 1.0f / (16.0f * (float)N_);
    for (int t = tid; t < 64 * 128; t += 256) {
        int nl = t & 63;
        int c = t >> 6;
        int g = c >> 4;
        float sum = gstats[(64 + b * 8 + g) * 2 + 0];
        float ssq = gstats[(64 + b * 8 + g) * 2 + 1];
        float mean = sum * invc;
        float var = ssq * invc - mean * mean;
        float rstd = rsqrtf(var + 1e-5f);
        size_t o = ((size_t)(b * 128 + c)) * N_ + n0 + nl;
        float v = (out[o] - mean) * rstd * scale[c] + bias[c];
        v = v / (1.f + __expf(-v));
        out[o] = v + vp[nl][c];
    }
}

extern "C" void kernel_launch(void* const* d_in, const int* in_sizes, int n_in,
                              void* d_out, int out_size, void* d_ws, size_t ws_size,
                              hipStream_t stream) {
    const float* coords   = (const float*)d_in[0];
    const float* features = (const float*)d_in[1];
    const float* conv1_w  = (const float*)d_in[2];
    const float* conv1_b  = (const float*)d_in[3];
    const float* gn1_s    = (const float*)d_in[4];
    const float* gn1_b    = (const float*)d_in[5];
    const float* conv2_w  = (const float*)d_in[6];
    const float* conv2_b  = (const float*)d_in[7];
    const float* gn2_s    = (const float*)d_in[8];
    const float* gn2_b    = (const float*)d_in[9];
    const float* point_w  = (const float*)d_in[10];
    const float* point_b  = (const float*)d_in[11];
    const float* pgn_s    = (const float*)d_in[12];
    const float* pgn_b    = (const float*)d_in[13];
    float* out = (float*)d_out;
    float* ws = (float*)d_ws;

    float*  nc     = ws + OFF_NC;
    int*    vidx   = (int*)(ws + OFF_VIDX);
    ushort* wt1    = (ushort*)(ws + OFF_WT1);
    ushort* wt2    = (ushort*)(ws + OFF_WT2);
    ushort* c2out  = (ushort*)(ws + OFF_C2OUT);
    float*  cnt    = ws + OFF_CNT;
    float*  gsum   = ws + OFF_GSUM;
    ushort* gpad   = (ushort*)(ws + OFF_GPAD);
    ushort* act1   = (ushort*)(ws + OFF_ACT1);
    float*  gstats = ws + OFF_GSTATS;
    float*  bstats = ws + OFF_BSTATS;

    const float invc = 1.0f / (float)(RRR_ * 16);

    hipMemsetAsync(cnt, 0, MEMSET_FLOATS * sizeof(float), stream);

    k_coord_sum<<<dim3(64, B_), 256, 0, stream>>>(coords, bstats);
    k_coord_max<<<dim3(64, B_), 256, 0, stream>>>(coords, bstats);
    k_point_prep<<<B_ * N_ / 256, 256, 0, stream>>>(coords, bstats, nc, vidx, cnt);
    k_scatter_cl<<<dim3(N_ / 128, B_), 256, 0, stream>>>(features, vidx, gsum);
    k_gridmean_cl<<<B_ * RRR_ * 16 / 256, 256, 0, stream>>>(gsum, cnt, gpad);

    k_wtrans<64><<<(27 * 128 * 64 + 255) / 256, 256, 0, stream>>>(conv1_w, wt1);
    k_wtrans<128><<<(27 * 128 * 128 + 255) / 256, 256, 0, stream>>>(conv2_w, wt2);

    k_conv<64, true><<<dim3(8, 32, B_), 256, 0, stream>>>(gpad, wt1, conv1_b, act1, gstats, 0);
    k_gn_apply<true><<<B_ * RRR_ * 16 / 256, 256, 0, stream>>>(act1, gstats, gn1_s, gn1_b, 0, invc);

    k_conv<128, false><<<dim3(8, 32, B_), 256, 0, stream>>>(act1, wt2, conv2_b, c2out, gstats, 1);
    k_gn_apply<false><<<B_ * RRR_ * 16 / 256, 256, 0, stream>>>(c2out, gstats, gn2_s, gn2_b, 1, invc);

    k_point_mlp<<<B_ * N_ / 256, 256, 0, stream>>>(features, point_w, point_b, out, gstats);
    k_devox_final<<<B_ * N_ / 64, 256, 0, stream>>>(nc, c2out, gstats, pgn_s, pgn_b, out);
}

// Round 8
// 1118.005 us; speedup vs baseline: 1.0056x; 1.0056x over previous
//
#include <hip/hip_runtime.h>

typedef __attribute__((ext_vector_type(8))) short bf16x8;
typedef __attribute__((ext_vector_type(4))) float f32x4;
typedef __attribute__((ext_vector_type(4))) int i32x4;
typedef __attribute__((ext_vector_type(2))) int i32x2;

#define B_ 4
#define N_ 65536
#define RRR_ 32768
#define PADV_ 39304   // 34^3
#define PPLANE_ 1156  // 34*34

// ---- workspace layout (float offsets) ----
static const size_t OFF_NC     = 0;         //  [4][3][65536] f32
static const size_t OFF_VIDX   = 786432;    //  [4][65536] int
static const size_t OFF_WT1    = 1048576;   //  [27][128][64] bf16 (quarter-swizzled rows)
static const size_t OFF_WT2    = 1159168;   //  [54][128][64] bf16 (quarter-swizzled rows)
static const size_t OFF_C2OUT  = 1380352;   //  [4][32768][128] bf16
// ---- memset region starts here ----
static const size_t OFF_CNT    = 9768960;   //  [4][32768] f32
static const size_t OFF_GSUM   = 9900032;   //  [4][32768][64] f32
static const size_t OFF_GPAD   = 18288640;  //  [4][39304][64] bf16
static const size_t OFF_ACT1   = 23319552;  //  [4][39304][128] bf16
static const size_t OFF_GSTATS = 33381376;  //  [3][4][8][2] f32 raw sum/ssq
static const size_t OFF_BSTATS = 33381568;  //  [4][4] f32 (sum x3, maxbits)
static const size_t MEMSET_FLOATS = 33381584 - 9768960;

__device__ __forceinline__ ushort f2bf(float x) {
    union { float f; unsigned u; } c; c.f = x;
    unsigned r = c.u + 0x7fffu + ((c.u >> 16) & 1u);
    return (ushort)(r >> 16);
}
__device__ __forceinline__ float bf2f(ushort h) {
    union { unsigned u; float f; } c; c.u = ((unsigned)h) << 16;
    return c.f;
}

__device__ __forceinline__ void gl16(const void* g, void* l) {
    __builtin_amdgcn_global_load_lds(
        (const __attribute__((address_space(1))) unsigned int*)(g),
        (__attribute__((address_space(3))) unsigned int*)(l),
        16, 0, 0);
}

// ---------------- coord partial sums ----------------
__global__ __launch_bounds__(256) void k_coord_sum(const float* __restrict__ coords,
                                                   float* __restrict__ bstats) {
    int b = blockIdx.y;
    int tid = threadIdx.x;
    const float* cb = coords + (size_t)b * 3 * N_;
    float s0 = 0.f, s1 = 0.f, s2 = 0.f;
    for (int n = blockIdx.x * 256 + tid; n < N_; n += 64 * 256) {
        s0 += cb[n]; s1 += cb[N_ + n]; s2 += cb[2 * N_ + n];
    }
    #pragma unroll
    for (int off = 1; off < 64; off <<= 1) {
        s0 += __shfl_xor(s0, off);
        s1 += __shfl_xor(s1, off);
        s2 += __shfl_xor(s2, off);
    }
    if ((tid & 63) == 0) {
        atomicAdd(&bstats[b * 4 + 0], s0);
        atomicAdd(&bstats[b * 4 + 1], s1);
        atomicAdd(&bstats[b * 4 + 2], s2);
    }
}

// ---------------- coord max-norm (after sums) ----------------
__global__ __launch_bounds__(256) void k_coord_max(const float* __restrict__ coords,
                                                   float* __restrict__ bstats) {
    int b = blockIdx.y;
    int tid = threadIdx.x;
    const float invN = 1.0f / (float)N_;
    float m0 = bstats[b * 4 + 0] * invN;
    float m1 = bstats[b * 4 + 1] * invN;
    float m2 = bstats[b * 4 + 2] * invN;
    const float* cb = coords + (size_t)b * 3 * N_;
    float mx = 0.f;
    for (int n = blockIdx.x * 256 + tid; n < N_; n += 64 * 256) {
        float x = cb[n] - m0, y = cb[N_ + n] - m1, z = cb[2 * N_ + n] - m2;
        mx = fmaxf(mx, x * x + y * y + z * z);
    }
    #pragma unroll
    for (int off = 1; off < 64; off <<= 1)
        mx = fmaxf(mx, __shfl_xor(mx, off));
    if ((tid & 63) == 0)
        atomicMax((int*)&bstats[b * 4 + 3], __float_as_int(mx));
}

// ---------------- normalized coords, voxel idx, counts ----------------
__global__ __launch_bounds__(256) void k_point_prep(const float* __restrict__ coords,
                                                    const float* __restrict__ bstats,
                                                    float* __restrict__ nc,
                                                    int* __restrict__ vidx,
                                                    float* __restrict__ cnt) {
    int gid = blockIdx.x * 256 + threadIdx.x;
    int b = gid >> 16;
    int n = gid & (N_ - 1);
    const float invN = 1.0f / (float)N_;
    float m[3] = {bstats[b * 4 + 0] * invN, bstats[b * 4 + 1] * invN, bstats[b * 4 + 2] * invN};
    float den = 2.0f * sqrtf(__int_as_float(((const int*)bstats)[b * 4 + 3]));
    const float* cb = coords + (size_t)b * 3 * N_;
    int vi[3];
    #pragma unroll
    for (int d = 0; d < 3; ++d) {
        float cv = cb[(size_t)d * N_ + n];
        float t = (cv - m[d]) / den + 0.5f;
        t *= 32.0f;
        t = fminf(fmaxf(t, 0.0f), 31.0f);
        nc[((size_t)b * 3 + d) * N_ + n] = t;
        vi[d] = (int)rintf(t);
    }
    int flat = (vi[0] * 32 + vi[1]) * 32 + vi[2];
    vidx[(b << 16) + n] = flat;
    atomicAdd(&cnt[(b << 15) + flat], 1.0f);
}

// ---------------- scatter-add features (channels-last, LDS staged) ----------------
__global__ __launch_bounds__(256) void k_scatter_cl(const float* __restrict__ feats,
                                                    const int* __restrict__ vidx,
                                                    float* __restrict__ gsum) {
    __shared__ float lf[64 * 129];
    __shared__ int sidx[128];
    int tid = threadIdx.x;
    int b = blockIdx.y;
    int n0 = blockIdx.x * 128;
    for (int i = tid; i < 64 * 128; i += 256) {
        int ci = i >> 7, pt = i & 127;
        lf[ci * 129 + pt] = feats[((size_t)(b * 64 + ci)) * N_ + n0 + pt];
    }
    if (tid < 128) sidx[tid] = vidx[(b << 16) + n0 + tid];
    __syncthreads();
    for (int i = tid; i < 64 * 128; i += 256) {
        int ci = i & 63, pt = i >> 6;
        atomicAdd(&gsum[((size_t)(b << 15) + sidx[pt]) * 64 + ci], lf[ci * 129 + pt]);
    }
}

// ---------------- sum -> mean, to padded bf16 channels-last ----------------
__global__ __launch_bounds__(256) void k_gridmean_cl(const float* __restrict__ gsum,
                                                     const float* __restrict__ cnt,
                                                     ushort* __restrict__ gpad) {
    int idx = blockIdx.x * 256 + threadIdx.x;     // 4*32768*16
    int q = idx & 15;
    int vox = (idx >> 4) & 32767;
    int b = idx >> 19;
    float c = cnt[(b << 15) + vox];
    float inv = 1.0f / fmaxf(c, 1.0f);
    float4 v = *(const float4*)(gsum + (((size_t)(b << 15) + vox) << 6) + q * 4);
    int zz = vox >> 10, yy = (vox >> 5) & 31, xx = vox & 31;
    size_t o = ((size_t)b * PADV_ + (size_t)(zz + 1) * PPLANE_ + (yy + 1) * 34 + (xx + 1)) * 64 + q * 4;
    i32x2 pk;
    ushort* u = (ushort*)&pk;
    u[0] = f2bf(v.x * inv); u[1] = f2bf(v.y * inv);
    u[2] = f2bf(v.z * inv); u[3] = f2bf(v.w * inv);
    *(i32x2*)(gpad + o) = pk;
}

// ---------------- weight transform to [ks][co][64ch window], quarter-swizzled ----------------
template <int CI>
__global__ __launch_bounds__(256) void k_wtrans(const float* __restrict__ w,
                                                ushort* __restrict__ wt) {
    int idx = blockIdx.x * 256 + threadIdx.x;
    if (idx >= 27 * 128 * CI) return;
    int e = idx & 7;
    int jm = (idx >> 3) & 7;
    int co = (idx >> 6) & 127;
    int ks = idx >> 13;
    int q = jm ^ (co & 7);
    int tap = (CI == 64) ? ks : (ks >> 1);
    int ci = ((CI == 64) ? 0 : ((ks & 1) * 64)) + q * 8 + e;
    wt[idx] = f2bf(w[((size_t)co * CI + ci) * 27 + tap]);
}

// ---------------- 3^3 conv as implicit GEMM, m97 structure ----------------
// block: 128 pos x 128 co, 256 thr / 4 waves; K-step 64.
// SINGLE 32KB buffer (A 16K + B 16K), 2 barriers per K-step, 5 blocks/CU.
// Source-side quarter swizzle (q ^ (row&7)); LDS linear; swizzled ds_read.
template <int CI, bool PAD_OUT>
__global__ __launch_bounds__(256, 5) void k_conv(const ushort* __restrict__ inp,
                                                 const ushort* __restrict__ wt,
                                                 const float* __restrict__ bias,
                                                 ushort* __restrict__ outp,
                                                 float* __restrict__ gstats,
                                                 int layer) {
    constexpr int NK = 27 * CI / 64;
    __shared__ char lds[32768];

    const int yg = blockIdx.x, z0 = blockIdx.y, b = blockIdx.z;
    const int y0 = yg * 4;
    const int tid = threadIdx.x;
    const int w = tid >> 6, l = tid & 63;
    const int lk = l >> 4, lr = l & 15;
    const int wr = w >> 1, wc = w & 1;

    const char* actb = (const char*)(inp + (size_t)b * PADV_ * CI);
    const char* wtb = (const char*)wt;

    // per-inst A global base (tap 0, window 0), source-side swizzle folded
    const char* agp[4];
    #pragma unroll
    for (int i = 0; i < 4; ++i) {
        int s = tid + i * 256;
        int row = s >> 3, j = s & 7;
        int jj = j ^ (row & 7);
        int py = row >> 5, px = row & 31;
        agp[i] = actb + ((size_t)(z0 * PPLANE_ + (y0 + py) * 34 + px) * CI) * 2 + jj * 16;
    }
    char* ldsAw = lds + w * 1024;            // + i*4096
    char* ldsBw = lds + 16384 + w * 1024;    // + i*4096

    // fragment read offsets (swizzled)
    int ard[4][2], brd[4][2];
    #pragma unroll
    for (int i = 0; i < 4; ++i) {
        int pos = wr * 64 + i * 16 + lr;
        #pragma unroll
        for (int kk = 0; kk < 2; ++kk)
            ard[i][kk] = pos * 128 + (((kk * 4 + lk) ^ (pos & 7)) << 4);
    }
    #pragma unroll
    for (int n = 0; n < 4; ++n) {
        int co = wc * 64 + n * 16 + lr;
        #pragma unroll
        for (int kk = 0; kk < 2; ++kk)
            brd[n][kk] = co * 128 + (((kk * 4 + lk) ^ (co & 7)) << 4);
    }

    f32x4 acc[4][4];
    #pragma unroll
    for (int i = 0; i < 4; ++i)
        #pragma unroll
        for (int n = 0; n < 4; ++n)
            acc[i][n] = (f32x4){0.f, 0.f, 0.f, 0.f};

    #pragma unroll 1
    for (int ks = 0; ks < NK; ++ks) {
        // stage A + B for this K-step
        {
            int tap = (CI == 64) ? ks : (ks >> 1);
            int choff2 = (CI == 64) ? 0 : ((ks & 1) << 7);
            int fz = tap / 9, r9 = tap - fz * 9;
            int fy = r9 / 3, fx = r9 - fy * 3;
            int ad = (fz * PPLANE_ + fy * 34 + fx) * CI * 2 + choff2;
            #pragma unroll
            for (int i = 0; i < 4; ++i)
                gl16(agp[i] + ad, ldsAw + i * 4096);
            const char* wsrc = wtb + (size_t)ks * 16384 + tid * 16;
            #pragma unroll
            for (int i = 0; i < 4; ++i)
                gl16(wsrc + i * 4096, ldsBw + i * 4096);
        }
        __syncthreads();   // drains vmcnt(0): loads landed
        #pragma unroll
        for (int kk = 0; kk < 2; ++kk) {
            bf16x8 af[4], bfr[4];
            #pragma unroll
            for (int i = 0; i < 4; ++i) af[i] = *(const bf16x8*)(lds + ard[i][kk]);
            #pragma unroll
            for (int n = 0; n < 4; ++n) bfr[n] = *(const bf16x8*)(lds + 16384 + brd[n][kk]);
            #pragma unroll
            for (int i = 0; i < 4; ++i)
                #pragma unroll
                for (int n = 0; n < 4; ++n)
                    acc[i][n] = __builtin_amdgcn_mfma_f32_16x16x32_bf16(af[i], bfr[n], acc[i][n], 0, 0, 0);
        }
        __syncthreads();   // all waves done reading before next stage overwrites
    }

    // ---- epilogue: bias + fused GN stats + bf16 pack via LDS + coalesced dump ----
    ushort* outs = (ushort*)lds;
    float bb[4];
    #pragma unroll
    for (int n = 0; n < 4; ++n) bb[n] = bias[wc * 64 + n * 16 + lr];
    float sg[4] = {0.f, 0.f, 0.f, 0.f}, sq[4] = {0.f, 0.f, 0.f, 0.f};
    #pragma unroll
    for (int i = 0; i < 4; ++i) {
        int posb = wr * 64 + i * 16 + lk * 4;
        #pragma unroll
        for (int n = 0; n < 4; ++n) {
            int co = wc * 64 + n * 16 + lr;
            #pragma unroll
            for (int r = 0; r < 4; ++r) {
                float v = acc[i][n][r] + bb[n];
                sg[n] += v; sq[n] += v * v;
                outs[(posb + r) * 128 + co] = f2bf(v);
            }
        }
    }
    #pragma unroll
    for (int off = 1; off < 64; off <<= 1) {
        #pragma unroll
        for (int n = 0; n < 4; ++n) {
            sg[n] += __shfl_xor(sg[n], off);
            sq[n] += __shfl_xor(sq[n], off);
        }
    }
    if (l == 0) {
        int gbase = layer * 32 + b * 8 + wc * 4;
        #pragma unroll
        for (int n = 0; n < 4; ++n) {
            atomicAdd(&gstats[(gbase + n) * 2 + 0], sg[n]);
            atomicAdd(&gstats[(gbase + n) * 2 + 1], sq[n]);
        }
    }
    __syncthreads();
    for (int idx = tid; idx < 2048; idx += 256) {
        int pos = idx >> 4, c8 = idx & 15;
        int yy = y0 + (pos >> 5), xx = pos & 31;
        size_t g;
        if (PAD_OUT)
            g = ((size_t)b * PADV_ + (size_t)(z0 + 1) * PPLANE_ + (yy + 1) * 34 + (xx + 1)) * 128 + c8 * 8;
        else
            g = ((size_t)b * RRR_ + z0 * 1024 + yy * 32 + xx) * 128 + c8 * 8;
        *(i32x4*)(outp + g) = *((i32x4*)lds + idx);
    }
}

// ---------------- GN + SiLU apply (channels-last bf16, padded or flat) ----------------
template <bool PAD>
__global__ __launch_bounds__(256) void k_gn_apply(ushort* __restrict__ x,
                                                  const float* __restrict__ gstats,
                                                  const float* __restrict__ sc,
                                                  const float* __restrict__ bi,
                                                  int layer, float invc) {
    int idx = blockIdx.x * 256 + threadIdx.x;   // 4*32768*16
    int c8 = idx & 15;
    int vox = (idx >> 4) & 32767;
    int b = idx >> 19;
    size_t base;
    if (PAD) {
        int zz = vox >> 10, yy = (vox >> 5) & 31, xx = vox & 31;
        base = ((size_t)b * PADV_ + (size_t)(zz + 1) * PPLANE_ + (yy + 1) * 34 + (xx + 1)) * 128 + c8 * 8;
    } else {
        base = ((size_t)b * RRR_ + vox) * 128 + c8 * 8;
    }
    int g = c8 >> 1;
    float sum = gstats[(layer * 32 + b * 8 + g) * 2 + 0];
    float ssq = gstats[(layer * 32 + b * 8 + g) * 2 + 1];
    float mean = sum * invc;
    float var = ssq * invc - mean * mean;
    float rstd = rsqrtf(var + 1e-5f);
    i32x4 raw = *(i32x4*)(x + base);
    ushort* u = (ushort*)&raw;
    #pragma unroll
    for (int j = 0; j < 8; ++j) {
        int co = c8 * 8 + j;
        float v = bf2f(u[j]);
        v = (v - mean) * rstd * sc[co] + bi[co];
        v = v / (1.f + __expf(-v));
        u[j] = f2bf(v);
    }
    *(i32x4*)(x + base) = raw;
}

// ---------------- point MLP (1x1 conv) + fused GN stats ----------------
__global__ __launch_bounds__(256) void k_point_mlp(const float* __restrict__ feats,
                                                   const float* __restrict__ w,
                                                   const float* __restrict__ pb,
                                                   float* __restrict__ out,
                                                   float* __restrict__ gstats) {
    __shared__ float wl[64 * 132];
    __shared__ float sred[4][16];
    int tid = threadIdx.x;
    for (int i = tid; i < 128 * 64; i += 256) {
        int o = i >> 6, c = i & 63;
        wl[c * 132 + o] = w[i];
    }
    __syncthreads();
    int gid = blockIdx.x * 256 + tid;
    int b = gid >> 16, n = gid & (N_ - 1);
    const float* fb = feats + (size_t)b * 64 * N_ + n;
    float acc[128];
    #pragma unroll
    for (int o = 0; o < 128; ++o) acc[o] = 0.f;
    for (int c = 0; c < 64; ++c) {
        float f = fb[(size_t)c * N_];
        const float4* wr4 = (const float4*)&wl[c * 132];
        #pragma unroll
        for (int o4 = 0; o4 < 32; ++o4) {
            float4 wv = wr4[o4];
            acc[4 * o4 + 0] = fmaf(f, wv.x, acc[4 * o4 + 0]);
            acc[4 * o4 + 1] = fmaf(f, wv.y, acc[4 * o4 + 1]);
            acc[4 * o4 + 2] = fmaf(f, wv.z, acc[4 * o4 + 2]);
            acc[4 * o4 + 3] = fmaf(f, wv.w, acc[4 * o4 + 3]);
        }
    }
    float* ob = out + (size_t)b * 128 * N_ + n;
    float sg[8] = {0.f}, sq[8] = {0.f};
    #pragma unroll
    for (int o = 0; o < 128; ++o) {
        float v = acc[o] + pb[o];
        ob[(size_t)o * N_] = v;
        sg[o >> 4] += v;
        sq[o >> 4] += v * v;
    }
    #pragma unroll
    for (int off = 1; off < 64; off <<= 1) {
        #pragma unroll
        for (int g = 0; g < 8; ++g) {
            sg[g] += __shfl_xor(sg[g], off);
            sq[g] += __shfl_xor(sq[g], off);
        }
    }
    int wv = tid >> 6, l = tid & 63;
    if (l == 0) {
        #pragma unroll
        for (int g = 0; g < 8; ++g) { sred[wv][g] = sg[g]; sred[wv][8 + g] = sq[g]; }
    }
    __syncthreads();
    if (tid < 16) {
        float v = sred[0][tid] + sred[1][tid] + sred[2][tid] + sred[3][tid];
        int g = tid & 7, part = tid >> 3;
        atomicAdd(&gstats[(64 + b * 8 + g) * 2 + part], v);
    }
}

// ---------------- devoxelize + point GN/SiLU + add ----------------
__global__ __launch_bounds__(256) void k_devox_final(const float* __restrict__ nc,
                                                     const ushort* __restrict__ ht,
                                                     const float* __restrict__ gstats,
                                                     const float* __restrict__ scale,
                                                     const float* __restrict__ bias,
                                                     float* __restrict__ out) {
    __shared__ float vp[64][129];
    __shared__ int sidx[64][8];
    __shared__ float swt[64][8];
    int tid = threadIdx.x;
    int blk = blockIdx.x;               // B * N/64 = 4096
    int b = blk >> 10;
    int n0 = (blk & 1023) * 64;
    if (tid < 64) {
        int n = n0 + tid;
        float f0 = nc[(size_t)b * 3 * N_ + n];
        float f1 = nc[((size_t)b * 3 + 1) * N_ + n];
        float f2 = nc[((size_t)b * 3 + 2) * N_ + n];
        float l0 = floorf(f0), l1 = floorf(f1), l2 = floorf(f2);
        float r0 = f0 - l0, r1 = f1 - l1, r2 = f2 - l2;
        int i0 = (int)l0, i1 = (int)l1, i2 = (int)l2;
        int h0 = min(i0 + 1, 31), h1 = min(i1 + 1, 31), h2 = min(i2 + 1, 31);
        #pragma unroll
        for (int k = 0; k < 8; ++k) {
            int dx = (k >> 2) & 1, dy = (k >> 1) & 1, dz = k & 1;
            int ix = dx ? h0 : i0, iy = dy ? h1 : i1, iz = dz ? h2 : i2;
            float w = (dx ? r0 : 1.f - r0) * (dy ? r1 : 1.f - r1) * (dz ? r2 : 1.f - r2);
            sidx[tid][k] = (ix * 32 + iy) * 32 + iz;
            swt[tid][k] = w;
        }
    }
    __syncthreads();
    const ushort* hb = ht + (size_t)b * RRR_ * 128;
    for (int t = tid; t < 64 * 16; t += 256) {
        int c8 = t & 15, pt = t >> 4;
        float a[8] = {0.f, 0.f, 0.f, 0.f, 0.f, 0.f, 0.f, 0.f};
        #pragma unroll
        for (int k = 0; k < 8; ++k) {
            i32x4 raw = *(const i32x4*)(hb + (size_t)sidx[pt][k] * 128 + c8 * 8);
            ushort* u = (ushort*)&raw;
            float wk = swt[pt][k];
            #pragma unroll
            for (int j = 0; j < 8; ++j)
                a[j] = fmaf(wk, bf2f(u[j]), a[j]);
        }
        #pragma unroll
        for (int j = 0; j < 8; ++j)
            vp[pt][c8 * 8 + j] = a[j];
    }
    __syncthreads();
    const float invc = 1.0f / (16.0f * (float)N_);
    for (int t = tid; t < 64 * 128; t += 256) {
        int nl = t & 63;
        int c = t >> 6;
        int g = c >> 4;
        float sum = gstats[(64 + b * 8 + g) * 2 + 0];
        float ssq = gstats[(64 + b * 8 + g) * 2 + 1];
        float mean = sum * invc;
        float var = ssq * invc - mean * mean;
        float rstd = rsqrtf(var + 1e-5f);
        size_t o = ((size_t)(b * 128 + c)) * N_ + n0 + nl;
        float v = (out[o] - mean) * rstd * scale[c] + bias[c];
        v = v / (1.f + __expf(-v));
        out[o] = v + vp[nl][c];
    }
}

extern "C" void kernel_launch(void* const* d_in, const int* in_sizes, int n_in,
                              void* d_out, int out_size, void* d_ws, size_t ws_size,
                              hipStream_t stream) {
    const float* coords   = (const float*)d_in[0];
    const float* features = (const float*)d_in[1];
    const float* conv1_w  = (const float*)d_in[2];
    const float* conv1_b  = (const float*)d_in[3];
    const float* gn1_s    = (const float*)d_in[4];
    const float* gn1_b    = (const float*)d_in[5];
    const float* conv2_w  = (const float*)d_in[6];
    const float* conv2_b  = (const float*)d_in[7];
    const float* gn2_s    = (const float*)d_in[8];
    const float* gn2_b    = (const float*)d_in[9];
    const float* point_w  = (const float*)d_in[10];
    const float* point_b  = (const float*)d_in[11];
    const float* pgn_s    = (const float*)d_in[12];
    const float* pgn_b    = (const float*)d_in[13];
    float* out = (float*)d_out;
    float* ws = (float*)d_ws;

    float*  nc     = ws + OFF_NC;
    int*    vidx   = (int*)(ws + OFF_VIDX);
    ushort* wt1    = (ushort*)(ws + OFF_WT1);
    ushort* wt2    = (ushort*)(ws + OFF_WT2);
    ushort* c2out  = (ushort*)(ws + OFF_C2OUT);
    float*  cnt    = ws + OFF_CNT;
    float*  gsum   = ws + OFF_GSUM;
    ushort* gpad   = (ushort*)(ws + OFF_GPAD);
    ushort* act1   = (ushort*)(ws + OFF_ACT1);
    float*  gstats = ws + OFF_GSTATS;
    float*  bstats = ws + OFF_BSTATS;

    const float invc = 1.0f / (float)(RRR_ * 16);

    hipMemsetAsync(cnt, 0, MEMSET_FLOATS * sizeof(float), stream);

    k_coord_sum<<<dim3(64, B_), 256, 0, stream>>>(coords, bstats);
    k_coord_max<<<dim3(64, B_), 256, 0, stream>>>(coords, bstats);
    k_point_prep<<<B_ * N_ / 256, 256, 0, stream>>>(coords, bstats, nc, vidx, cnt);
    k_scatter_cl<<<dim3(N_ / 128, B_), 256, 0, stream>>>(features, vidx, gsum);
    k_gridmean_cl<<<B_ * RRR_ * 16 / 256, 256, 0, stream>>>(gsum, cnt, gpad);

    k_wtrans<64><<<(27 * 128 * 64 + 255) / 256, 256, 0, stream>>>(conv1_w, wt1);
    k_wtrans<128><<<(27 * 128 * 128 + 255) / 256, 256, 0, stream>>>(conv2_w, wt2);

    k_conv<64, true><<<dim3(8, 32, B_), 256, 0, stream>>>(gpad, wt1, conv1_b, act1, gstats, 0);
    k_gn_apply<true><<<B_ * RRR_ * 16 / 256, 256, 0, stream>>>(act1, gstats, gn1_s, gn1_b, 0, invc);

    k_conv<128, false><<<dim3(8, 32, B_), 256, 0, stream>>>(act1, wt2, conv2_b, c2out, gstats, 1);
    k_gn_apply<false><<<B_ * RRR_ * 16 / 256, 256, 0, stream>>>(c2out, gstats, gn2_s, gn2_b, 1, invc);

    k_point_mlp<<<B_ * N_ / 256, 256, 0, stream>>>(features, point_w, point_b, out, gstats);
    k_devox_final<<<B_ * N_ / 64, 256, 0, stream>>>(nc, c2out, gstats, pgn_s, pgn_b, out);
}

// Round 9
// 1057.412 us; speedup vs baseline: 1.0632x; 1.0573x over previous
//
#include <hip/hip_runtime.h>

typedef __attribute__((ext_vector_type(8))) short bf16x8;
typedef __attribute__((ext_vector_type(4))) float f32x4;
typedef __attribute__((ext_vector_type(4))) int i32x4;
typedef __attribute__((ext_vector_type(2))) int i32x2;

#define B_ 4
#define N_ 65536
#define RRR_ 32768
#define PADV_ 39304   // 34^3
#define PPLANE_ 1156  // 34*34

// ---- workspace layout (float offsets) ----
static const size_t OFF_NC     = 0;         //  [4][3][65536] f32
static const size_t OFF_VIDX   = 786432;    //  [4][65536] int
static const size_t OFF_WT1    = 1048576;   //  [27][128][64] bf16 (quarter-swizzled rows)
static const size_t OFF_WT2    = 1159168;   //  [54][128][64] bf16 (quarter-swizzled rows)
static const size_t OFF_C2OUT  = 1380352;   //  [4][32768][128] bf16
// ---- memset region starts here ----
static const size_t OFF_CNT    = 9768960;   //  [4][32768] f32
static const size_t OFF_GSUM   = 9900032;   //  [4][32768][64] f32
static const size_t OFF_GPAD   = 18288640;  //  [4][39304][64] bf16
static const size_t OFF_ACT1   = 23319552;  //  [4][39304][128] bf16
static const size_t OFF_GSTATS = 33381376;  //  [3][4][8][2] f32 raw sum/ssq
static const size_t OFF_BSTATS = 33381568;  //  [4][4] f32 (sum x3, maxbits)
static const size_t MEMSET_FLOATS = 33381584 - 9768960;

__device__ __forceinline__ ushort f2bf(float x) {
    union { float f; unsigned u; } c; c.f = x;
    unsigned r = c.u + 0x7fffu + ((c.u >> 16) & 1u);
    return (ushort)(r >> 16);
}
__device__ __forceinline__ float bf2f(ushort h) {
    union { unsigned u; float f; } c; c.u = ((unsigned)h) << 16;
    return c.f;
}

__device__ __forceinline__ void gl16(const void* g, void* l) {
    __builtin_amdgcn_global_load_lds(
        (const __attribute__((address_space(1))) unsigned int*)(g),
        (__attribute__((address_space(3))) unsigned int*)(l),
        16, 0, 0);
}

// ---------------- coord partial sums ----------------
__global__ __launch_bounds__(256) void k_coord_sum(const float* __restrict__ coords,
                                                   float* __restrict__ bstats) {
    int b = blockIdx.y;
    int tid = threadIdx.x;
    const float* cb = coords + (size_t)b * 3 * N_;
    float s0 = 0.f, s1 = 0.f, s2 = 0.f;
    for (int n = blockIdx.x * 256 + tid; n < N_; n += 64 * 256) {
        s0 += cb[n]; s1 += cb[N_ + n]; s2 += cb[2 * N_ + n];
    }
    #pragma unroll
    for (int off = 1; off < 64; off <<= 1) {
        s0 += __shfl_xor(s0, off);
        s1 += __shfl_xor(s1, off);
        s2 += __shfl_xor(s2, off);
    }
    if ((tid & 63) == 0) {
        atomicAdd(&bstats[b * 4 + 0], s0);
        atomicAdd(&bstats[b * 4 + 1], s1);
        atomicAdd(&bstats[b * 4 + 2], s2);
    }
}

// ---------------- coord max-norm (after sums) ----------------
__global__ __launch_bounds__(256) void k_coord_max(const float* __restrict__ coords,
                                                   float* __restrict__ bstats) {
    int b = blockIdx.y;
    int tid = threadIdx.x;
    const float invN = 1.0f / (float)N_;
    float m0 = bstats[b * 4 + 0] * invN;
    float m1 = bstats[b * 4 + 1] * invN;
    float m2 = bstats[b * 4 + 2] * invN;
    const float* cb = coords + (size_t)b * 3 * N_;
    float mx = 0.f;
    for (int n = blockIdx.x * 256 + tid; n < N_; n += 64 * 256) {
        float x = cb[n] - m0, y = cb[N_ + n] - m1, z = cb[2 * N_ + n] - m2;
        mx = fmaxf(mx, x * x + y * y + z * z);
    }
    #pragma unroll
    for (int off = 1; off < 64; off <<= 1)
        mx = fmaxf(mx, __shfl_xor(mx, off));
    if ((tid & 63) == 0)
        atomicMax((int*)&bstats[b * 4 + 3], __float_as_int(mx));
}

// ---------------- normalized coords, voxel idx, counts ----------------
__global__ __launch_bounds__(256) void k_point_prep(const float* __restrict__ coords,
                                                    const float* __restrict__ bstats,
                                                    float* __restrict__ nc,
                                                    int* __restrict__ vidx,
                                                    float* __restrict__ cnt) {
    int gid = blockIdx.x * 256 + threadIdx.x;
    int b = gid >> 16;
    int n = gid & (N_ - 1);
    const float invN = 1.0f / (float)N_;
    float m[3] = {bstats[b * 4 + 0] * invN, bstats[b * 4 + 1] * invN, bstats[b * 4 + 2] * invN};
    float den = 2.0f * sqrtf(__int_as_float(((const int*)bstats)[b * 4 + 3]));
    const float* cb = coords + (size_t)b * 3 * N_;
    int vi[3];
    #pragma unroll
    for (int d = 0; d < 3; ++d) {
        float cv = cb[(size_t)d * N_ + n];
        float t = (cv - m[d]) / den + 0.5f;
        t *= 32.0f;
        t = fminf(fmaxf(t, 0.0f), 31.0f);
        nc[((size_t)b * 3 + d) * N_ + n] = t;
        vi[d] = (int)rintf(t);
    }
    int flat = (vi[0] * 32 + vi[1]) * 32 + vi[2];
    vidx[(b << 16) + n] = flat;
    atomicAdd(&cnt[(b << 15) + flat], 1.0f);
}

// ---------------- scatter-add features (channels-last, LDS staged) ----------------
__global__ __launch_bounds__(256) void k_scatter_cl(const float* __restrict__ feats,
                                                    const int* __restrict__ vidx,
                                                    float* __restrict__ gsum) {
    __shared__ float lf[64 * 129];
    __shared__ int sidx[128];
    int tid = threadIdx.x;
    int b = blockIdx.y;
    int n0 = blockIdx.x * 128;
    for (int i = tid; i < 64 * 128; i += 256) {
        int ci = i >> 7, pt = i & 127;
        lf[ci * 129 + pt] = feats[((size_t)(b * 64 + ci)) * N_ + n0 + pt];
    }
    if (tid < 128) sidx[tid] = vidx[(b << 16) + n0 + tid];
    __syncthreads();
    for (int i = tid; i < 64 * 128; i += 256) {
        int ci = i & 63, pt = i >> 6;
        atomicAdd(&gsum[((size_t)(b << 15) + sidx[pt]) * 64 + ci], lf[ci * 129 + pt]);
    }
}

// ---------------- sum -> mean, to padded bf16 channels-last ----------------
__global__ __launch_bounds__(256) void k_gridmean_cl(const float* __restrict__ gsum,
                                                     const float* __restrict__ cnt,
                                                     ushort* __restrict__ gpad) {
    int idx = blockIdx.x * 256 + threadIdx.x;     // 4*32768*16
    int q = idx & 15;
    int vox = (idx >> 4) & 32767;
    int b = idx >> 19;
    float c = cnt[(b << 15) + vox];
    float inv = 1.0f / fmaxf(c, 1.0f);
    float4 v = *(const float4*)(gsum + (((size_t)(b << 15) + vox) << 6) + q * 4);
    int zz = vox >> 10, yy = (vox >> 5) & 31, xx = vox & 31;
    size_t o = ((size_t)b * PADV_ + (size_t)(zz + 1) * PPLANE_ + (yy + 1) * 34 + (xx + 1)) * 64 + q * 4;
    i32x2 pk;
    ushort* u = (ushort*)&pk;
    u[0] = f2bf(v.x * inv); u[1] = f2bf(v.y * inv);
    u[2] = f2bf(v.z * inv); u[3] = f2bf(v.w * inv);
    *(i32x2*)(gpad + o) = pk;
}

// ---------------- weight transform to [ks][co][64ch window], quarter-swizzled ----------------
template <int CI>
__global__ __launch_bounds__(256) void k_wtrans(const float* __restrict__ w,
                                                ushort* __restrict__ wt) {
    int idx = blockIdx.x * 256 + threadIdx.x;
    if (idx >= 27 * 128 * CI) return;
    int e = idx & 7;
    int jm = (idx >> 3) & 7;
    int co = (idx >> 6) & 127;
    int ks = idx >> 13;
    int q = jm ^ (co & 7);
    int tap = (CI == 64) ? ks : (ks >> 1);
    int ci = ((CI == 64) ? 0 : ((ks & 1) * 64)) + q * 8 + e;
    wt[idx] = f2bf(w[((size_t)co * CI + ci) * 27 + tap]);
}

// ---------------- 3^3 conv as implicit GEMM, m97 structure + XCD-chunked swizzle ----------------
// block: 128 pos x 128 co, 256 thr / 4 waves; K-step 64.
// SINGLE 32KB buffer (A 16K + B 16K), 2 barriers per K-step.
// 1D grid 1024 blocks; wid = (bid&7)*128 + (bid>>3): XCD k gets a contiguous
// 128-block chunk = 16 consecutive z-slabs of one batch -> A slabs stay in that
// XCD's private L2 (fixes the 8.5x HBM over-fetch measured in round 8).
template <int CI, bool PAD_OUT>
__global__ __launch_bounds__(256, 5) void k_conv(const ushort* __restrict__ inp,
                                                 const ushort* __restrict__ wt,
                                                 const float* __restrict__ bias,
                                                 ushort* __restrict__ outp,
                                                 float* __restrict__ gstats,
                                                 int layer) {
    constexpr int NK = 27 * CI / 64;
    __shared__ char lds[32768];

    const int bid = blockIdx.x;
    const int wid = (bid & 7) * 128 + (bid >> 3);      // 1024 % 8 == 0: bijective
    const int yg = wid & 7;
    const int z0 = (wid >> 3) & 31;
    const int b = wid >> 8;
    const int y0 = yg * 4;
    const int tid = threadIdx.x;
    const int w = tid >> 6, l = tid & 63;
    const int lk = l >> 4, lr = l & 15;
    const int wr = w >> 1, wc = w & 1;

    const char* actb = (const char*)(inp + (size_t)b * PADV_ * CI);
    const char* wtb = (const char*)wt;

    // per-inst A global base (tap 0, window 0), source-side swizzle folded
    const char* agp[4];
    #pragma unroll
    for (int i = 0; i < 4; ++i) {
        int s = tid + i * 256;
        int row = s >> 3, j = s & 7;
        int jj = j ^ (row & 7);
        int py = row >> 5, px = row & 31;
        agp[i] = actb + ((size_t)(z0 * PPLANE_ + (y0 + py) * 34 + px) * CI) * 2 + jj * 16;
    }
    char* ldsAw = lds + w * 1024;            // + i*4096
    char* ldsBw = lds + 16384 + w * 1024;    // + i*4096

    // fragment read offsets (swizzled)
    int ard[4][2], brd[4][2];
    #pragma unroll
    for (int i = 0; i < 4; ++i) {
        int pos = wr * 64 + i * 16 + lr;
        #pragma unroll
        for (int kk = 0; kk < 2; ++kk)
            ard[i][kk] = pos * 128 + (((kk * 4 + lk) ^ (pos & 7)) << 4);
    }
    #pragma unroll
    for (int n = 0; n < 4; ++n) {
        int co = wc * 64 + n * 16 + lr;
        #pragma unroll
        for (int kk = 0; kk < 2; ++kk)
            brd[n][kk] = co * 128 + (((kk * 4 + lk) ^ (co & 7)) << 4);
    }

    f32x4 acc[4][4];
    #pragma unroll
    for (int i = 0; i < 4; ++i)
        #pragma unroll
        for (int n = 0; n < 4; ++n)
            acc[i][n] = (f32x4){0.f, 0.f, 0.f, 0.f};

    #pragma unroll 1
    for (int ks = 0; ks < NK; ++ks) {
        // stage A + B for this K-step
        {
            int tap = (CI == 64) ? ks : (ks >> 1);
            int choff2 = (CI == 64) ? 0 : ((ks & 1) << 7);
            int fz = tap / 9, r9 = tap - fz * 9;
            int fy = r9 / 3, fx = r9 - fy * 3;
            int ad = (fz * PPLANE_ + fy * 34 + fx) * CI * 2 + choff2;
            #pragma unroll
            for (int i = 0; i < 4; ++i)
                gl16(agp[i] + ad, ldsAw + i * 4096);
            const char* wsrc = wtb + (size_t)ks * 16384 + tid * 16;
            #pragma unroll
            for (int i = 0; i < 4; ++i)
                gl16(wsrc + i * 4096, ldsBw + i * 4096);
        }
        __syncthreads();   // drains vmcnt(0): loads landed
        #pragma unroll
        for (int kk = 0; kk < 2; ++kk) {
            bf16x8 af[4], bfr[4];
            #pragma unroll
            for (int i = 0; i < 4; ++i) af[i] = *(const bf16x8*)(lds + ard[i][kk]);
            #pragma unroll
            for (int n = 0; n < 4; ++n) bfr[n] = *(const bf16x8*)(lds + 16384 + brd[n][kk]);
            #pragma unroll
            for (int i = 0; i < 4; ++i)
                #pragma unroll
                for (int n = 0; n < 4; ++n)
                    acc[i][n] = __builtin_amdgcn_mfma_f32_16x16x32_bf16(af[i], bfr[n], acc[i][n], 0, 0, 0);
        }
        __syncthreads();   // all waves done reading before next stage overwrites
    }

    // ---- epilogue: bias + fused GN stats + bf16 pack via LDS + coalesced dump ----
    ushort* outs = (ushort*)lds;
    float bb[4];
    #pragma unroll
    for (int n = 0; n < 4; ++n) bb[n] = bias[wc * 64 + n * 16 + lr];
    float sg[4] = {0.f, 0.f, 0.f, 0.f}, sq[4] = {0.f, 0.f, 0.f, 0.f};
    #pragma unroll
    for (int i = 0; i < 4; ++i) {
        int posb = wr * 64 + i * 16 + lk * 4;
        #pragma unroll
        for (int n = 0; n < 4; ++n) {
            int co = wc * 64 + n * 16 + lr;
            #pragma unroll
            for (int r = 0; r < 4; ++r) {
                float v = acc[i][n][r] + bb[n];
                sg[n] += v; sq[n] += v * v;
                outs[(posb + r) * 128 + co] = f2bf(v);
            }
        }
    }
    #pragma unroll
    for (int off = 1; off < 64; off <<= 1) {
        #pragma unroll
        for (int n = 0; n < 4; ++n) {
            sg[n] += __shfl_xor(sg[n], off);
            sq[n] += __shfl_xor(sq[n], off);
        }
    }
    if (l == 0) {
        int gbase = layer * 32 + b * 8 + wc * 4;
        #pragma unroll
        for (int n = 0; n < 4; ++n) {
            atomicAdd(&gstats[(gbase + n) * 2 + 0], sg[n]);
            atomicAdd(&gstats[(gbase + n) * 2 + 1], sq[n]);
        }
    }
    __syncthreads();
    for (int idx = tid; idx < 2048; idx += 256) {
        int pos = idx >> 4, c8 = idx & 15;
        int yy = y0 + (pos >> 5), xx = pos & 31;
        size_t g;
        if (PAD_OUT)
            g = ((size_t)b * PADV_ + (size_t)(z0 + 1) * PPLANE_ + (yy + 1) * 34 + (xx + 1)) * 128 + c8 * 8;
        else
            g = ((size_t)b * RRR_ + z0 * 1024 + yy * 32 + xx) * 128 + c8 * 8;
        *(i32x4*)(outp + g) = *((i32x4*)lds + idx);
    }
}

// ---------------- GN + SiLU apply (channels-last bf16, padded or flat) ----------------
template <bool PAD>
__global__ __launch_bounds__(256) void k_gn_apply(ushort* __restrict__ x,
                                                  const float* __restrict__ gstats,
                                                  const float* __restrict__ sc,
                                                  const float* __restrict__ bi,
                                                  int layer, float invc) {
    int idx = blockIdx.x * 256 + threadIdx.x;   // 4*32768*16
    int c8 = idx & 15;
    int vox = (idx >> 4) & 32767;
    int b = idx >> 19;
    size_t base;
    if (PAD) {
        int zz = vox >> 10, yy = (vox >> 5) & 31, xx = vox & 31;
        base = ((size_t)b * PADV_ + (size_t)(zz + 1) * PPLANE_ + (yy + 1) * 34 + (xx + 1)) * 128 + c8 * 8;
    } else {
        base = ((size_t)b * RRR_ + vox) * 128 + c8 * 8;
    }
    int g = c8 >> 1;
    float sum = gstats[(layer * 32 + b * 8 + g) * 2 + 0];
    float ssq = gstats[(layer * 32 + b * 8 + g) * 2 + 1];
    float mean = sum * invc;
    float var = ssq * invc - mean * mean;
    float rstd = rsqrtf(var + 1e-5f);
    i32x4 raw = *(i32x4*)(x + base);
    ushort* u = (ushort*)&raw;
    #pragma unroll
    for (int j = 0; j < 8; ++j) {
        int co = c8 * 8 + j;
        float v = bf2f(u[j]);
        v = (v - mean) * rstd * sc[co] + bi[co];
        v = v / (1.f + __expf(-v));
        u[j] = f2bf(v);
    }
    *(i32x4*)(x + base) = raw;
}

// ---------------- point MLP (1x1 conv) + fused GN stats ----------------
__global__ __launch_bounds__(256) void k_point_mlp(const float* __restrict__ feats,
                                                   const float* __restrict__ w,
                                                   const float* __restrict__ pb,
                                                   float* __restrict__ out,
                                                   float* __restrict__ gstats) {
    __shared__ float wl[64 * 132];
    __shared__ float sred[4][16];
    int tid = threadIdx.x;
    for (int i = tid; i < 128 * 64; i += 256) {
        int o = i >> 6, c = i & 63;
        wl[c * 132 + o] = w[i];
    }
    __syncthreads();
    int gid = blockIdx.x * 256 + tid;
    int b = gid >> 16, n = gid & (N_ - 1);
    const float* fb = feats + (size_t)b * 64 * N_ + n;
    float acc[128];
    #pragma unroll
    for (int o = 0; o < 128; ++o) acc[o] = 0.f;
    for (int c = 0; c < 64; ++c) {
        float f = fb[(size_t)c * N_];
        const float4* wr4 = (const float4*)&wl[c * 132];
        #pragma unroll
        for (int o4 = 0; o4 < 32; ++o4) {
            float4 wv = wr4[o4];
            acc[4 * o4 + 0] = fmaf(f, wv.x, acc[4 * o4 + 0]);
            acc[4 * o4 + 1] = fmaf(f, wv.y, acc[4 * o4 + 1]);
            acc[4 * o4 + 2] = fmaf(f, wv.z, acc[4 * o4 + 2]);
            acc[4 * o4 + 3] = fmaf(f, wv.w, acc[4 * o4 + 3]);
        }
    }
    float* ob = out + (size_t)b * 128 * N_ + n;
    float sg[8] = {0.f}, sq[8] = {0.f};
    #pragma unroll
    for (int o = 0; o < 128; ++o) {
        float v = acc[o] + pb[o];
        ob[(size_t)o * N_] = v;
        sg[o >> 4] += v;
        sq[o >> 4] += v * v;
    }
    #pragma unroll
    for (int off = 1; off < 64; off <<= 1) {
        #pragma unroll
        for (int g = 0; g < 8; ++g) {
            sg[g] += __shfl_xor(sg[g], off);
            sq[g] += __shfl_xor(sq[g], off);
        }
    }
    int wv = tid >> 6, l = tid & 63;
    if (l == 0) {
        #pragma unroll
        for (int g = 0; g < 8; ++g) { sred[wv][g] = sg[g]; sred[wv][8 + g] = sq[g]; }
    }
    __syncthreads();
    if (tid < 16) {
        float v = sred[0][tid] + sred[1][tid] + sred[2][tid] + sred[3][tid];
        int g = tid & 7, part = tid >> 3;
        atomicAdd(&gstats[(64 + b * 8 + g) * 2 + part], v);
    }
}

// ---------------- devoxelize + point GN/SiLU + add ----------------
__global__ __launch_bounds__(256) void k_devox_final(const float* __restrict__ nc,
                                                     const ushort* __restrict__ ht,
                                                     const float* __restrict__ gstats,
                                                     const float* __restrict__ scale,
                                                     const float* __restrict__ bias,
                                                     float* __restrict__ out) {
    __shared__ float vp[64][129];
    __shared__ int sidx[64][8];
    __shared__ float swt[64][8];
    int tid = threadIdx.x;
    int blk = blockIdx.x;               // B * N/64 = 4096
    int b = blk >> 10;
    int n0 = (blk & 1023) * 64;
    if (tid < 64) {
        int n = n0 + tid;
        float f0 = nc[(size_t)b * 3 * N_ + n];
        float f1 = nc[((size_t)b * 3 + 1) * N_ + n];
        float f2 = nc[((size_t)b * 3 + 2) * N_ + n];
        float l0 = floorf(f0), l1 = floorf(f1), l2 = floorf(f2);
        float r0 = f0 - l0, r1 = f1 - l1, r2 = f2 - l2;
        int i0 = (int)l0, i1 = (int)l1, i2 = (int)l2;
        int h0 = min(i0 + 1, 31), h1 = min(i1 + 1, 31), h2 = min(i2 + 1, 31);
        #pragma unroll
        for (int k = 0; k < 8; ++k) {
            int dx = (k >> 2) & 1, dy = (k >> 1) & 1, dz = k & 1;
            int ix = dx ? h0 : i0, iy = dy ? h1 : i1, iz = dz ? h2 : i2;
            float w = (dx ? r0 : 1.f - r0) * (dy ? r1 : 1.f - r1) * (dz ? r2 : 1.f - r2);
            sidx[tid][k] = (ix * 32 + iy) * 32 + iz;
            swt[tid][k] = w;
        }
    }
    __syncthreads();
    const ushort* hb = ht + (size_t)b * RRR_ * 128;
    for (int t = tid; t < 64 * 16; t += 256) {
        int c8 = t & 15, pt = t >> 4;
        float a[8] = {0.f, 0.f, 0.f, 0.f, 0.f, 0.f, 0.f, 0.f};
        #pragma unroll
        for (int k = 0; k < 8; ++k) {
            i32x4 raw = *(const i32x4*)(hb + (size_t)sidx[pt][k] * 128 + c8 * 8);
            ushort* u = (ushort*)&raw;
            float wk = swt[pt][k];
            #pragma unroll
            for (int j = 0; j < 8; ++j)
                a[j] = fmaf(wk, bf2f(u[j]), a[j]);
        }
        #pragma unroll
        for (int j = 0; j < 8; ++j)
            vp[pt][c8 * 8 + j] = a[j];
    }
    __syncthreads();
    const float invc = 1.0f / (16.0f * (float)N_);
    for (int t = tid; t < 64 * 128; t += 256) {
        int nl = t & 63;
        int c = t >> 6;
        int g = c >> 4;
        float sum = gstats[(64 + b * 8 + g) * 2 + 0];
        float ssq = gstats[(64 + b * 8 + g) * 2 + 1];
        float mean = sum * invc;
        float var = ssq * invc - mean * mean;
        float rstd = rsqrtf(var + 1e-5f);
        size_t o = ((size_t)(b * 128 + c)) * N_ + n0 + nl;
        float v = (out[o] - mean) * rstd * scale[c] + bias[c];
        v = v / (1.f + __expf(-v));
        out[o] = v + vp[nl][c];
    }
}

extern "C" void kernel_launch(void* const* d_in, const int* in_sizes, int n_in,
                              void* d_out, int out_size, void* d_ws, size_t ws_size,
                              hipStream_t stream) {
    const float* coords   = (const float*)d_in[0];
    const float* features = (const float*)d_in[1];
    const float* conv1_w  = (const float*)d_in[2];
    const float* conv1_b  = (const float*)d_in[3];
    const float* gn1_s    = (const float*)d_in[4];
    const float* gn1_b    = (const float*)d_in[5];
    const float* conv2_w  = (const float*)d_in[6];
    const float* conv2_b  = (const float*)d_in[7];
    const float* gn2_s    = (const float*)d_in[8];
    const float* gn2_b    = (const float*)d_in[9];
    const float* point_w  = (const float*)d_in[10];
    const float* point_b  = (const float*)d_in[11];
    const float* pgn_s    = (const float*)d_in[12];
    const float* pgn_b    = (const float*)d_in[13];
    float* out = (float*)d_out;
    float* ws = (float*)d_ws;

    float*  nc     = ws + OFF_NC;
    int*    vidx   = (int*)(ws + OFF_VIDX);
    ushort* wt1    = (ushort*)(ws + OFF_WT1);
    ushort* wt2    = (ushort*)(ws + OFF_WT2);
    ushort* c2out  = (ushort*)(ws + OFF_C2OUT);
    float*  cnt    = ws + OFF_CNT;
    float*  gsum   = ws + OFF_GSUM;
    ushort* gpad   = (ushort*)(ws + OFF_GPAD);
    ushort* act1   = (ushort*)(ws + OFF_ACT1);
    float*  gstats = ws + OFF_GSTATS;
    float*  bstats = ws + OFF_BSTATS;

    const float invc = 1.0f / (float)(RRR_ * 16);

    hipMemsetAsync(cnt, 0, MEMSET_FLOATS * sizeof(float), stream);

    k_coord_sum<<<dim3(64, B_), 256, 0, stream>>>(coords, bstats);
    k_coord_max<<<dim3(64, B_), 256, 0, stream>>>(coords, bstats);
    k_point_prep<<<B_ * N_ / 256, 256, 0, stream>>>(coords, bstats, nc, vidx, cnt);
    k_scatter_cl<<<dim3(N_ / 128, B_), 256, 0, stream>>>(features, vidx, gsum);
    k_gridmean_cl<<<B_ * RRR_ * 16 / 256, 256, 0, stream>>>(gsum, cnt, gpad);

    k_wtrans<64><<<(27 * 128 * 64 + 255) / 256, 256, 0, stream>>>(conv1_w, wt1);
    k_wtrans<128><<<(27 * 128 * 128 + 255) / 256, 256, 0, stream>>>(conv2_w, wt2);

    k_conv<64, true><<<1024, 256, 0, stream>>>(gpad, wt1, conv1_b, act1, gstats, 0);
    k_gn_apply<true><<<B_ * RRR_ * 16 / 256, 256, 0, stream>>>(act1, gstats, gn1_s, gn1_b, 0, invc);

    k_conv<128, false><<<1024, 256, 0, stream>>>(act1, wt2, conv2_b, c2out, gstats, 1);
    k_gn_apply<false><<<B_ * RRR_ * 16 / 256, 256, 0, stream>>>(c2out, gstats, gn2_s, gn2_b, 1, invc);

    k_point_mlp<<<B_ * N_ / 256, 256, 0, stream>>>(features, point_w, point_b, out, gstats);
    k_devox_final<<<B_ * N_ / 64, 256, 0, stream>>>(nc, c2out, gstats, pgn_s, pgn_b, out);
}